// Round 8
// baseline (41.166 us; speedup 1.0000x reference)
//
#include <hip/hip_runtime.h>

// out[b,s,:] = W[:, text[b,s]] + bias + pe[s,:]
// text: int32 [B,S]; W: f32 [D, VOCAB]; bias: f32 [D]; pe: f32 [MAX_LEN, D]
//
// Round 8: r7 structure, but 512B-contiguous W stage reads (VT=128) AND full
// 32 waves/CU occupancy (512-thread blocks, 4 x 33.3KB LDS/CU). LDS tile is
// TRANSPOSED [v][d] with stride 65 so the process-phase column read stays
// conflict-free; stage scalar writes are ~4-way (hidden under load latency).

#define VOCAB  32000
#define DMODEL 1024
#define S_LEN  2048
#define B_N    4
#define NTOK   (B_N * S_LEN)     // 8192
#define VT     128               // vocab entries per tile
#define DT     64                // d rows per tile
#define NBIN   (VOCAB / VT)      // 250
#define NDT    (DMODEL / DT)     // 16
#define NBLK   (NBIN * NDT)      // 4000
#define LSTRIDE (DT + 1)         // 65: transposed rows, process read 2-way max

// ---- pass 1: bin tokens by 128-wide vocab tile (single block) ----
__global__ __launch_bounds__(1024) void bin_k(const int* __restrict__ text,
                                              int2* __restrict__ sorted,
                                              int* __restrict__ tile_off) {
    __shared__ int cnt[256];
    __shared__ int scn[256];
    const int t = threadIdx.x;
    if (t < 256) cnt[t] = 0;
    __syncthreads();

    int toks[8];
    #pragma unroll
    for (int j = 0; j < 8; ++j) {
        toks[j] = text[t * 8 + j];
        atomicAdd(&cnt[toks[j] >> 7], 1);
    }
    __syncthreads();

    if (t < 256) scn[t] = cnt[t];
    __syncthreads();
    for (int off = 1; off < 256; off <<= 1) {
        int x = 0;
        if (t < 256 && t >= off) x = scn[t - off];
        __syncthreads();
        if (t < 256) scn[t] += x;
        __syncthreads();
    }
    if (t < 256) {
        const int start = scn[t] - cnt[t];   // exclusive
        tile_off[t] = start;                 // tile_off[250] = 8192
        cnt[t] = start;                      // running cursor
    }
    __syncthreads();

    #pragma unroll
    for (int j = 0; j < 8; ++j) {
        const int tok = toks[j];
        const int slot = atomicAdd(&cnt[tok >> 7], 1);
        sorted[slot] = make_int2(tok, t * 8 + j);
    }
}

// ---- pass 2: coalesced W sweep (512B chunks), scatter-free gather ----
__global__ __launch_bounds__(512, 8) void gather_k(const int2* __restrict__ sorted,
                                                   const int* __restrict__ tile_off,
                                                   const float* __restrict__ W,
                                                   const float* __restrict__ bias,
                                                   const float* __restrict__ pe,
                                                   float* __restrict__ out) {
    __shared__ float lds[VT * LSTRIDE];      // 128 x 65 x 4B = 33.3 KB

    const int bid = blockIdx.x;
    const int vt = bid >> 4;                 // 0..249
    const int dt = bid & (NDT - 1);          // 0..15 (bid%8 ~ dt%8 -> XCD: pe L2-local)
    const int v0 = vt * VT;
    const int d0 = dt * DT;
    const int t  = threadIdx.x;

    // stage W[d0:d0+64][v0:v0+128] into transposed LDS [v][d]
    // read: 32 float4/row -> 512B contiguous per wave-instruction
    {
        const int c4 = t & 31;               // float4 column 0..31
        const int r0 = t >> 5;               // row 0..15
        #pragma unroll
        for (int i = 0; i < 4; ++i) {
            const int row = r0 + i * 16;
            const float4 w4 = *reinterpret_cast<const float4*>(
                W + (size_t)(d0 + row) * VOCAB + v0 + c4 * 4);
            float* lp = lds + (c4 * 4) * LSTRIDE + row;   // transposed
            lp[0 * LSTRIDE] = w4.x;
            lp[1 * LSTRIDE] = w4.y;
            lp[2 * LSTRIDE] = w4.z;
            lp[3 * LSTRIDE] = w4.w;
        }
    }
    __syncthreads();

    const int a0 = tile_off[vt];
    const int a1 = tile_off[vt + 1];
    const int lane = t & 63;                 // = d within tile
    const int wv   = t >> 6;                 // 8 tokens in parallel
    const float bv = bias[d0 + lane];

    for (int i = a0 + wv; i < a1; i += 8) {
        const int2 p = sorted[i];            // wave-uniform broadcast
        const int tokl = p.x - v0;
        const int bs   = p.y;
        const int s    = bs & (S_LEN - 1);
        const float wval = lds[tokl * LSTRIDE + lane];   // (tokl+lane)%32: 2-way
        const float pv = pe[(size_t)s * DMODEL + d0 + lane];
        out[(size_t)bs * DMODEL + d0 + lane] = wval + bv + pv;
    }
}

// ---- fallback (ws too small): direct gather ----
__global__ __launch_bounds__(256) void embed_pe_direct(const int* __restrict__ text,
                                                       const float* __restrict__ W,
                                                       const float* __restrict__ bias,
                                                       const float* __restrict__ pe,
                                                       float* __restrict__ out) {
    const int bs = blockIdx.x;
    const int s  = bs & (S_LEN - 1);
    const int tok = text[bs];
    const int d = threadIdx.x << 2;
    const float4 b4 = *reinterpret_cast<const float4*>(bias + d);
    const float4 p4 = *reinterpret_cast<const float4*>(pe + (size_t)s * DMODEL + d);
    const float* wcol = W + (size_t)d * VOCAB + tok;
    float4 o;
    o.x = wcol[0]                 + b4.x + p4.x;
    o.y = wcol[(size_t)VOCAB]     + b4.y + p4.y;
    o.z = wcol[(size_t)2 * VOCAB] + b4.z + p4.z;
    o.w = wcol[(size_t)3 * VOCAB] + b4.w + p4.w;
    *reinterpret_cast<float4*>(out + (size_t)bs * DMODEL + d) = o;
}

extern "C" void kernel_launch(void* const* d_in, const int* in_sizes, int n_in,
                              void* d_out, int out_size, void* d_ws, size_t ws_size,
                              hipStream_t stream) {
    const int*   text = (const int*)d_in[0];
    const float* W    = (const float*)d_in[1];
    const float* bias = (const float*)d_in[2];
    const float* pe   = (const float*)d_in[3];
    float*       out  = (float*)d_out;

    const size_t sorted_bytes = (size_t)NTOK * sizeof(int2);   // 64 KB
    const size_t off_bytes    = 257 * sizeof(int);
    if (ws_size < sorted_bytes + off_bytes) {
        embed_pe_direct<<<NTOK, 256, 0, stream>>>(text, W, bias, pe, out);
        return;
    }

    int2* sorted   = (int2*)d_ws;
    int*  tile_off = (int*)((char*)d_ws + sorted_bytes);

    bin_k   <<<1, 1024, 0, stream>>>(text, sorted, tile_off);
    gather_k<<<NBLK, 512, 0, stream>>>(sorted, tile_off, W, bias, pe, out);
}